// Round 17
// baseline (251.744 us; speedup 1.0000x reference)
//
#include <hip/hip_runtime.h>

#define S_LEN 4096
#define NH 12
#define HDIM 64
#define DMODEL 768
#define NEGF -1.0e9f
#define TOK0_SPLITS 16
#define RSTH 16777216.0f  // 2^24 overflow guard for no-rmax softmax fast path

typedef __attribute__((ext_vector_type(8))) short bf16x8;
typedef __attribute__((ext_vector_type(4))) float f32x4;

__device__ __forceinline__ short f2b(float f) {
  union { float f; unsigned u; } v; v.f = f;
  unsigned r = v.u + 0x7fffu + ((v.u >> 16) & 1u);
  return (short)(r >> 16);
}
__device__ __forceinline__ float b2f(short s) {
  union { unsigned u; float f; } v; v.u = ((unsigned)(unsigned short)s) << 16;
  return v.f;
}

// ---------- fused preprocessing: conv_x | weight-transpose | mask-bias | qg ----------
__global__ __launch_bounds__(256) void k_pre(const float* __restrict__ x,
                                             const float* __restrict__ Wq,
                                             const float* __restrict__ Wk,
                                             const float* __restrict__ Wv,
                                             const float* __restrict__ Wkg,
                                             const float* __restrict__ Wvg,
                                             const float* __restrict__ Wo,
                                             const float* __restrict__ Wqg,
                                             const int* __restrict__ amask,
                                             short* __restrict__ xb,
                                             short* __restrict__ W5t,
                                             short* __restrict__ Wot,
                                             float* __restrict__ qg,
                                             float* __restrict__ mvb) {
  __shared__ float smem[1056];
  int bid = blockIdx.x, tid = threadIdx.x;
  if (bid < 6144) {  // ---- x f32 -> bf16 (x4) ----
    int i = bid * 256 + tid;
    float4 v = ((const float4*)x)[i];
    ((short4*)xb)[i] = make_short4(f2b(v.x), f2b(v.y), f2b(v.z), f2b(v.w));
  } else if (bid < 9600) {  // ---- weight transpose+convert ----
    int zb = bid - 6144;
    int z = zb / 576, rem = zb - z * 576;
    int by = rem / 24, bx = rem - by * 24;
    const float* src; float scale = 1.f; short* dst;
    switch (z) {
      case 0: src = Wq;  scale = 0.125f * 1.44269504f; dst = W5t; break;
      case 1: src = Wk;  dst = W5t + 589824; break;
      case 2: src = Wv;  dst = W5t + 2 * 589824; break;
      case 3: src = Wkg; dst = W5t + 3 * 589824; break;
      case 4: src = Wvg; dst = W5t + 4 * 589824; break;
      default: src = Wo; dst = Wot; break;
    }
    int tx = tid & 31, ty = tid >> 5;
    int kb = by * 32, nb = bx * 32;
    for (int i = 0; i < 4; i++) smem[(ty + 8 * i) * 33 + tx] = src[(kb + ty + 8 * i) * 768 + nb + tx];
    __syncthreads();
    for (int i = 0; i < 4; i++)
      dst[(nb + ty + 8 * i) * 768 + kb + tx] = f2b(smem[tx * 33 + ty + 8 * i] * scale);
  } else if (bid < 9632) {  // ---- mask bias ----
    int zb = bid - 9600;
    int b = zb >> 4, s = (zb & 15) * 256 + tid;
    mvb[b * S_LEN + s] = (s != 0 && amask[b * S_LEN + s] > 0) ? 0.f : NEGF;
  } else {  // ---- qg = x[b,0,:] @ Wqg * 0.125 ----
    int zb = bid - 9632;
    int h = zb % 12, b = zb / 12;
    int out = tid & 63, slice = tid >> 6;
    float* xr = smem;          // 768
    float* ps = smem + 768;    // 4*64
    for (int i = tid; i < 768; i += 256) xr[i] = x[(long)b * S_LEN * 768 + i];
    __syncthreads();
    float a = 0.f;
    int n = h * 64 + out;
#pragma unroll 8
    for (int k = slice * 192; k < slice * 192 + 192; k++) a += xr[k] * Wqg[k * 768 + n];
    ps[slice * 64 + out] = a;
    __syncthreads();
    if (tid < 64)
      qg[b * 768 + h * 64 + tid] = (ps[tid] + ps[64 + tid] + ps[128 + tid] + ps[192 + tid]) * 0.125f;
  }
}

// ---------- 256x128-tile bf16 GEMM: 8 waves (4Mx2N), proven 2-phase schedule ----------
__global__ __launch_bounds__(512) void k_gemm3(const short* __restrict__ A,
                                               const short* __restrict__ Bt, int K, int mode,
                                               short* __restrict__ qkv, float* __restrict__ outf) {
  __shared__ short Al[2][256 * 32];
  __shared__ short Bl[2][128 * 32];
  int bid = blockIdx.x;
  int xcd = bid & 7, ii = bid >> 3;
  int bm = xcd * 4 + (ii & 3), bn = ii >> 2;
  int tid = threadIdx.x;
  int bm0 = bm * 256, bn0 = bn * 128;
  int w = tid >> 6, lane = tid & 63, g = lane >> 4, r16 = lane & 15;
  int wm = w >> 1, wn = w & 1;
  f32x4 zero4 = {0.f, 0.f, 0.f, 0.f};
  f32x4 acc[4][4];
  for (int m = 0; m < 4; m++) for (int n = 0; n < 4; n++) acc[m][n] = zero4;
  int srow = tid >> 2;          // 0..127
  int scol = (tid & 3) * 8;     // 16B chunks
#define G_STAGE3(BUF, KT)                                                             \
  do {                                                                                \
    const short* ga0 = &A[(long)(bm0 + srow) * K + (KT) + scol];                      \
    __builtin_amdgcn_global_load_lds(                                                 \
        (const __attribute__((address_space(1))) void*)ga0,                           \
        (__attribute__((address_space(3))) void*)&Al[BUF][srow * 32 + scol], 16, 0, 0);\
    const short* ga1 = &A[(long)(bm0 + 128 + srow) * K + (KT) + scol];                \
    __builtin_amdgcn_global_load_lds(                                                 \
        (const __attribute__((address_space(1))) void*)ga1,                           \
        (__attribute__((address_space(3))) void*)&Al[BUF][(128 + srow) * 32 + scol],  \
        16, 0, 0);                                                                    \
    const short* gb = &Bt[(long)(bn0 + srow) * K + (KT) + scol];                      \
    __builtin_amdgcn_global_load_lds(                                                 \
        (const __attribute__((address_space(1))) void*)gb,                            \
        (__attribute__((address_space(3))) void*)&Bl[BUF][srow * 32 + scol], 16, 0, 0);\
  } while (0)
  int nt = K >> 5;
  G_STAGE3(0, 0);
  __syncthreads();
  int cur = 0;
  for (int t = 0; t < nt; t++) {
    if (t + 1 < nt) G_STAGE3(cur ^ 1, (t + 1) * 32);
    bf16x8 af[4], bfv[4];
    for (int m = 0; m < 4; m++)
      af[m] = *(const bf16x8*)&Al[cur][(wm * 64 + m * 16 + r16) * 32 + g * 8];
    for (int n = 0; n < 4; n++)
      bfv[n] = *(const bf16x8*)&Bl[cur][(wn * 64 + n * 16 + r16) * 32 + g * 8];
    for (int m = 0; m < 4; m++)
      for (int n = 0; n < 4; n++)
        acc[m][n] = __builtin_amdgcn_mfma_f32_16x16x32_bf16(af[m], bfv[n], acc[m][n], 0, 0, 0);
    __syncthreads();
    cur ^= 1;
  }
#undef G_STAGE3
  for (int m = 0; m < 4; m++)
    for (int n = 0; n < 4; n++)
      for (int reg = 0; reg < 4; reg++) {
        int row = bm0 + wm * 64 + m * 16 + g * 4 + reg;
        int col = bn0 + wn * 64 + n * 16 + r16;
        float val = acc[m][n][reg];
        if (mode == 0) {
          int proj = col / 768;
          int rem = col - proj * 768;
          int hh = rem >> 6, d = rem & 63;
          int bb = row >> 12, s = row & 4095;
          qkv[(long)proj * 6291456 + ((((long)bb * NH + hh) * S_LEN + s) << 6) + d] = f2b(val);
        } else {
          outf[(long)row * 768 + col] = val;
        }
      }
}

// ---------- 128x128-tile bf16 GEMM (proven; kept for the small output proj) ----------
__global__ __launch_bounds__(256) void k_gemm(const short* __restrict__ A,
                                              const short* __restrict__ Bt, int K, int mode,
                                              short* __restrict__ qkv, float* __restrict__ outf) {
  __shared__ short Al[2][128 * 32];
  __shared__ short Bl[2][128 * 32];
  int bid = blockIdx.x;
  int xcd = bid & 7, ii = bid >> 3;
  int bm = xcd * 8 + (ii & 7), bn = ii >> 3;
  int tid = threadIdx.x;
  int bm0 = bm * 128, bn0 = bn * 128;
  int w = tid >> 6, lane = tid & 63, g = lane >> 4, r16 = lane & 15;
  int wr = (w >> 1) * 64, wc = (w & 1) * 64;
  f32x4 zero4 = {0.f, 0.f, 0.f, 0.f};
  f32x4 acc[4][4];
  for (int m = 0; m < 4; m++) for (int n = 0; n < 4; n++) acc[m][n] = zero4;
  int srow = w * 32 + (lane >> 2);
  int scol = (lane & 3) * 8;
#define G_STAGE(BUF, KT)                                                              \
  do {                                                                                \
    for (int i = 0; i < 2; i++) {                                                     \
      const short* ga = &A[(long)(bm0 + srow + i * 16) * K + (KT) + scol];            \
      const short* gb = &Bt[(long)(bn0 + srow + i * 16) * K + (KT) + scol];           \
      __builtin_amdgcn_global_load_lds(                                               \
          (const __attribute__((address_space(1))) void*)ga,                          \
          (__attribute__((address_space(3))) void*)&Al[BUF][(w * 32 + i * 16) * 32],  \
          16, 0, 0);                                                                  \
      __builtin_amdgcn_global_load_lds(                                               \
          (const __attribute__((address_space(1))) void*)gb,                          \
          (__attribute__((address_space(3))) void*)&Bl[BUF][(w * 32 + i * 16) * 32],  \
          16, 0, 0);                                                                  \
    }                                                                                 \
  } while (0)
  int nt = K >> 5;
  G_STAGE(0, 0);
  __syncthreads();
  int cur = 0;
  for (int t = 0; t < nt; t++) {
    if (t + 1 < nt) G_STAGE(cur ^ 1, (t + 1) * 32);
    bf16x8 af[4], bfv[4];
    for (int m = 0; m < 4; m++) af[m] = *(const bf16x8*)&Al[cur][(wr + m * 16 + r16) * 32 + g * 8];
    for (int n = 0; n < 4; n++) bfv[n] = *(const bf16x8*)&Bl[cur][(wc + n * 16 + r16) * 32 + g * 8];
    for (int m = 0; m < 4; m++)
      for (int n = 0; n < 4; n++)
        acc[m][n] = __builtin_amdgcn_mfma_f32_16x16x32_bf16(af[m], bfv[n], acc[m][n], 0, 0, 0);
    __syncthreads();
    cur ^= 1;
  }
#undef G_STAGE
  for (int m = 0; m < 4; m++)
    for (int n = 0; n < 4; n++)
      for (int reg = 0; reg < 4; reg++) {
        int row = bm0 + wr + m * 16 + g * 4 + reg;
        int col = bn0 + wc + n * 16 + r16;
        float val = acc[m][n][reg];
        if (mode == 0) {
          int proj = col / 768;
          int rem = col - proj * 768;
          int hh = rem >> 6, d = rem & 63;
          int bb = row >> 12, s = row & 4095;
          qkv[(long)proj * 6291456 + ((((long)bb * NH + hh) * S_LEN + s) << 6) + d] = f2b(val);
        } else {
          outf[(long)row * 768 + col] = val;
        }
      }
}

// ---------- V transpose: Vt[b,h,d,s] from V[b,h,s,d] ----------
__global__ __launch_bounds__(256) void k_vt(const short* __restrict__ V, short* __restrict__ Vt) {
  __shared__ short buf[64][72];
  int st = blockIdx.x, bh = blockIdx.y;
  int tid = threadIdx.x;
  long base = (long)bh * S_LEN * HDIM;
  int s0 = st * 64;
  int r = tid >> 2, c = (tid & 3) * 16;
  *(int4*)&buf[r][c]     = *(const int4*)&V[base + (long)(s0 + r) * HDIM + c];
  *(int4*)&buf[r][c + 8] = *(const int4*)&V[base + (long)(s0 + r) * HDIM + c + 8];
  __syncthreads();
  int d = tid >> 2, sc = (tid & 3) * 16;
  short tmp[16];
#pragma unroll
  for (int j = 0; j < 16; j++) tmp[j] = buf[sc + j][d];
  long ob = base + (long)d * S_LEN + s0 + sc;
  *(int4*)&Vt[ob]     = *(const int4*)&tmp[0];
  *(int4*)&Vt[ob + 8] = *(const int4*)&tmp[8];
}

#define PSTRIDE 68 // Plds row stride (shorts)

// ---------- band attention per-chunk compute: no-rmax fast path + guarded fallback ----------
__device__ __forceinline__ void band_chunk(
    int ks0, int qrow0, int g, int r16,
    const bf16x8 (&qf)[2][2], const bf16x8 (&kf)[4][2], const bf16x8 (&vf)[4][2],
    const float (&mv)[4],
    float (&mstate)[2][4], float (&lstate)[2][4], f32x4 (&acc)[2][4],
    short* Plds) {
  int dlo = ks0 - qrow0;
  bool fullok = (dlo >= -224) && (dlo <= 192);  // wave-uniform
  for (int m = 0; m < 2; m++) {
    f32x4 s[4];
    f32x4 zero4 = {0.f, 0.f, 0.f, 0.f};
    for (int n = 0; n < 4; n++) {
      f32x4 z = __builtin_amdgcn_mfma_f32_16x16x32_bf16(qf[m][0], kf[n][0], zero4, 0, 0, 0);
      s[n] = __builtin_amdgcn_mfma_f32_16x16x32_bf16(qf[m][1], kf[n][1], z, 0, 0, 0);
    }
    float p[4][4];
    float rs[4] = {0.f, 0.f, 0.f, 0.f};
    int qbase = qrow0 + m * 16 + g * 4;
    if (fullok) {
      for (int n = 0; n < 4; n++)
        for (int reg = 0; reg < 4; reg++) {
          float e = __builtin_amdgcn_exp2f(s[n][reg] + mv[n] - mstate[m][reg]);
          p[n][reg] = e;
          rs[reg] += e;
        }
    } else {
      for (int n = 0; n < 4; n++) {
        int kpos = ks0 + n * 16 + r16;
        for (int reg = 0; reg < 4; reg++) {
          int qpos = qbase + reg;
          bool ok = (kpos >= qpos - 256) && (kpos <= qpos + 256);
          float e = ok ? __builtin_amdgcn_exp2f(s[n][reg] + mv[n] - mstate[m][reg]) : 0.f;
          p[n][reg] = e;
          rs[reg] += e;
        }
      }
    }
    bool ovf = (rs[0] > RSTH) || (rs[1] > RSTH) || (rs[2] > RSTH) || (rs[3] > RSTH);
    if (__any((int)ovf)) {
      // slow fallback: full online-softmax update recomputed from s (rare)
      float rmax[4];
      for (int reg = 0; reg < 4; reg++) rmax[reg] = NEGF;
      for (int n = 0; n < 4; n++) {
        int kpos = ks0 + n * 16 + r16;
        for (int reg = 0; reg < 4; reg++) {
          int qpos = qbase + reg;
          bool ok = fullok || ((kpos >= qpos - 256) && (kpos <= qpos + 256));
          float val = ok ? (s[n][reg] + mv[n]) : NEGF;
          rmax[reg] = fmaxf(rmax[reg], val);
        }
      }
      for (int reg = 0; reg < 4; reg++) {
        float r = rmax[reg];
        r = fmaxf(r, __shfl_xor(r, 1));
        r = fmaxf(r, __shfl_xor(r, 2));
        r = fmaxf(r, __shfl_xor(r, 4));
        r = fmaxf(r, __shfl_xor(r, 8));
        rmax[reg] = r;
      }
      float scal[4];
      for (int reg = 0; reg < 4; reg++) {
        float mn = fmaxf(mstate[m][reg], rmax[reg]);
        scal[reg] = __builtin_amdgcn_exp2f(mstate[m][reg] - mn);
        mstate[m][reg] = mn;
        rs[reg] = 0.f;
      }
      for (int n = 0; n < 4; n++) {
        int kpos = ks0 + n * 16 + r16;
        for (int reg = 0; reg < 4; reg++) {
          int qpos = qbase + reg;
          bool ok = fullok || ((kpos >= qpos - 256) && (kpos <= qpos + 256));
          float e = ok ? __builtin_amdgcn_exp2f(s[n][reg] + mv[n] - mstate[m][reg]) : 0.f;
          p[n][reg] = e;
          rs[reg] += e;
        }
      }
      for (int reg = 0; reg < 4; reg++) {
        float r = rs[reg];
        r += __shfl_xor(r, 1);
        r += __shfl_xor(r, 2);
        r += __shfl_xor(r, 4);
        r += __shfl_xor(r, 8);
        lstate[m][reg] = lstate[m][reg] * scal[reg] + r;
      }
      for (int n = 0; n < 4; n++)
        for (int reg = 0; reg < 4; reg++) acc[m][n][reg] *= scal[reg];
    } else {  // common path: no rmax, no rescale
      for (int reg = 0; reg < 4; reg++) {
        float r = rs[reg];
        r += __shfl_xor(r, 1);
        r += __shfl_xor(r, 2);
        r += __shfl_xor(r, 4);
        r += __shfl_xor(r, 8);
        lstate[m][reg] += r;
      }
    }
    for (int n = 0; n < 4; n++)
      for (int reg = 0; reg < 4; reg++)
        Plds[(g * 4 + reg) * PSTRIDE + n * 16 + r16] = f2b(p[n][reg]);
    bf16x8 pa[2];
    for (int ks = 0; ks < 2; ks++)
      pa[ks] = *(const bf16x8*)&Plds[r16 * PSTRIDE + ks * 32 + g * 8];
    for (int n = 0; n < 4; n++)
      for (int ks = 0; ks < 2; ks++)
        acc[m][n] = __builtin_amdgcn_mfma_f32_16x16x32_bf16(pa[ks], vf[n][ks], acc[m][n], 0, 0, 0);
  }
}

// ---------- fused attention: band 2-way split-KV (bid<1536) + tok0 (bid>=1536) ----------
// Band chunk loop is 2-deep software-pipelined: next chunk's K/V/mv loads issue
// (into the OTHER named register set, rule #20) before current chunk's compute,
// giving them ~QK+softmax+PV of latency cover. VGPR budget: launch_bounds(256,2)
// allows 256/wave; ~124 base + ~68 B-set fits spill-free (tripwire: WRITE_SIZE).
// min-waves MUST stay 2: bound 4 caps VGPR at 64 -> 590MB scratch (R9).
__global__ __launch_bounds__(256, 2) void k_attn(const short* __restrict__ Qb,
                                                 const short* __restrict__ Kb,
                                                 const short* __restrict__ Vb,
                                                 const short* __restrict__ Vtb,
                                                 const short* __restrict__ Kg,
                                                 const short* __restrict__ Vg,
                                                 const float* __restrict__ qg,
                                                 const int* __restrict__ amask,
                                                 const float* __restrict__ mvb,
                                                 short* __restrict__ oattn,
                                                 float* __restrict__ part) {
  __shared__ short Plds[4][16 * PSTRIDE];
  __shared__ float mrg[2][48][65];
  __shared__ float fsm[592];
  int bid = blockIdx.x, tid = threadIdx.x;
  if (bid < 1536) {
    // ================= band path (2-way split-KV, 2-deep pipelined) =================
    int qt = bid & 63, rest = bid >> 6;
    int h = rest % NH, b = rest / NH;
    int w = tid >> 6, lane = tid & 63, g = lane >> 4, r16 = lane & 15;
    int pair = w >> 1;   // q-subtile (0: rows +0, 1: rows +32)
    int par = w & 1;     // KV-split parity
    long bhof = ((long)(b * NH + h)) * S_LEN * HDIM;
    int qrow0 = qt * 64 + pair * 32;

    bf16x8 qf[2][2];
    for (int m = 0; m < 2; m++)
      for (int ks = 0; ks < 2; ks++)
        qf[m][ks] = *(const bf16x8*)&Qb[bhof + (long)(qrow0 + m * 16 + r16) * HDIM + ks * 32 + g * 8];

    float mstate[2][4], lstate[2][4];
    f32x4 acc[2][4];
    if (par == 0) {  // parity 0 owns the global key-0 column init (clamped for fast path)
      bf16x8 k0f[2];
      for (int ks = 0; ks < 2; ks++) k0f[ks] = *(const bf16x8*)&Kb[bhof + ks * 32 + g * 8];
      float part0[2];
      for (int m = 0; m < 2; m++) {
        float p = 0.f;
        for (int ks = 0; ks < 2; ks++)
          for (int j = 0; j < 8; j++) p += b2f(qf[m][ks][j]) * b2f(k0f[ks][j]);
        p += __shfl_xor(p, 16);
        p += __shfl_xor(p, 32);
        part0[m] = p;
      }
      float mask0 = (amask[b * S_LEN] > 0) ? 0.f : NEGF;
      float v0v[4];
      for (int n = 0; n < 4; n++) v0v[n] = b2f(Vb[bhof + n * 16 + r16]);
      for (int m = 0; m < 2; m++)
        for (int reg = 0; reg < 4; reg++) {
          float m0raw = __shfl(part0[m], g * 4 + reg) + mask0;
          float m0 = fmaxf(m0raw, -60.f);  // clamp so fast-path exp2 stays finite
          mstate[m][reg] = m0;
          float l0 = __builtin_amdgcn_exp2f(m0raw - m0);
          lstate[m][reg] = l0;
          for (int n = 0; n < 4; n++) acc[m][n][reg] = l0 * v0v[n];
        }
    } else {  // parity 1: m=0 (finite: fast path needs it), l=0, acc=0
      for (int m = 0; m < 2; m++)
        for (int reg = 0; reg < 4; reg++) {
          mstate[m][reg] = 0.f;
          lstate[m][reg] = 0.f;
          for (int n = 0; n < 4; n++) acc[m][n][reg] = 0.f;
        }
    }

    int wlo = (qrow0 - 256) >> 6; if (wlo < 0) wlo = 0;
    int whi = (qrow0 + 31 + 256) >> 6; if (whi > 63) whi = 63;

    bf16x8 kfA[4][2], vfA[4][2], kfB[4][2], vfB[4][2];
    float mvA[4], mvB[4];
#define BLOAD(KF, VF, MV, CI)                                                                   \
    do {                                                                                        \
      int _k = (CI) * 64;                                                                       \
      for (int n = 0; n < 4; n++)                                                               \
        for (int ks = 0; ks < 2; ks++) {                                                        \
          VF[n][ks] = *(const bf16x8*)&Vtb[bhof + (long)(n * 16 + r16) * S_LEN + _k + ks * 32 + g * 8]; \
          KF[n][ks] = *(const bf16x8*)&Kb[bhof + (long)(_k + n * 16 + r16) * HDIM + ks * 32 + g * 8];   \
        }                                                                                       \
      for (int n = 0; n < 4; n++) MV[n] = mvb[b * S_LEN + _k + n * 16 + r16];                   \
    } while (0)

    int ci = wlo + par;
    if (ci <= whi) BLOAD(kfA, vfA, mvA, ci);
    while (ci <= whi) {
      if (ci + 2 <= whi) BLOAD(kfB, vfB, mvB, ci + 2);
      band_chunk(ci * 64, qrow0, g, r16, qf, kfA, vfA, mvA, mstate, lstate, acc, &Plds[w][0]);
      ci += 2;
      if (ci > whi) break;
      if (ci + 2 <= whi) BLOAD(kfA, vfA, mvA, ci + 2);
      band_chunk(ci * 64, qrow0, g, r16, qf, kfB, vfB, mvB, mstate, lstate, acc, &Plds[w][0]);
      ci += 2;
    }
#undef BLOAD

    // merge parity-1 state into parity-0, then write
    if (par == 1) {
      for (int m = 0; m < 2; m++)
        for (int reg = 0; reg < 4; reg++) {
          mrg[pair][m * 4 + reg][lane] = mstate[m][reg];
          mrg[pair][8 + m * 4 + reg][lane] = lstate[m][reg];
          for (int n = 0; n < 4; n++)
            mrg[pair][16 + m * 16 + n * 4 + reg][lane] = acc[m][n][reg];
        }
    }
    __syncthreads();
    if (par == 0) {
      for (int m = 0; m < 2; m++)
        for (int reg = 0; reg < 4; reg++) {
          float mB = mrg[pair][m * 4 + reg][lane];
          float lB = mrg[pair][8 + m * 4 + reg][lane];
          float M = fmaxf(mstate[m][reg], mB);
          float sA = __builtin_amdgcn_exp2f(mstate[m][reg] - M);
          float sB = __builtin_amdgcn_exp2f(mB - M);
          float l = lstate[m][reg] * sA + lB * sB;
          int token = qrow0 + m * 16 + g * 4 + reg;
          for (int n = 0; n < 4; n++) {
            float a = acc[m][n][reg] * sA + mrg[pair][16 + m * 16 + n * 4 + reg][lane] * sB;
            int col = h * 64 + n * 16 + r16;
            oattn[((long)b * S_LEN + token) * 768 + col] = f2b(a / l);
          }
        }
    }
  } else {
    // ================= token-0 global attention partials =================
    int tbid = bid - 1536;
    int split = tbid & 15, bhid = tbid >> 4;
    int b = bhid / NH, h = bhid % NH;
    long base = (long)bhid * S_LEN * HDIM;
    int lane = tid & 63, w = tid >> 6;
    int s = split * 256 + tid;
    float* qgl  = fsm;        // 64
    float* p_sh = fsm + 64;   // 256
    float* red  = fsm + 320;  // 4
    float* psum = fsm + 324;  // 4*64
    if (tid < 64) qgl[tid] = qg[b * 768 + h * 64 + tid];
    __syncthreads();
    float dot = 0.f;
    {
      const int4* kr = (const int4*)&Kg[base + (long)s * HDIM];
#pragma unroll
      for (int u = 0; u < 8; u++) {
        int4 pk = kr[u];
        const short* sp = (const short*)&pk;
        for (int j = 0; j < 8; j++) dot += qgl[u * 8 + j] * b2f(sp[j]);
      }
      dot += (amask[b * S_LEN + s] > 0) ? 0.f : NEGF;
    }
    float mx = dot;
    for (int o = 32; o; o >>= 1) mx = fmaxf(mx, __shfl_xor(mx, o));
    if (lane == 0) red[w] = mx;
    __syncthreads();
    mx = fmaxf(fmaxf(red[0], red[1]), fmaxf(red[2], red[3]));
    float e = __expf(dot - mx);
    p_sh[tid] = e;
    float sum = e;
    for (int o = 32; o; o >>= 1) sum += __shfl_xor(sum, o);
    __syncthreads();
    if (lane == 0) red[w] = sum;
    __syncthreads();
    sum = red[0] + red[1] + red[2] + red[3];
    int d = tid & 63, grp = tid >> 6;
    float a = 0.f;
    long vb = base + (long)(split * 256 + grp * 64) * HDIM + d;
#pragma unroll 8
    for (int j = 0; j < 64; j++) a += p_sh[grp * 64 + j] * b2f(Vg[vb + (long)j * HDIM]);
    psum[grp * 64 + d] = a;
    __syncthreads();
    float* dst = &part[((long)bhid * TOK0_SPLITS + split) * 66];
    if (tid == 0) { dst[0] = mx; dst[1] = sum; }
    if (tid < 64)
      dst[2 + tid] = psum[tid] + psum[64 + tid] + psum[128 + tid] + psum[192 + tid];
  }
}

__global__ void k_tok0_comb(const float* __restrict__ part, short* __restrict__ oattn) {
  int bhid = blockIdx.x, d = threadIdx.x;
  int b = bhid / NH, h = bhid % NH;
  const float* p0 = &part[(long)bhid * TOK0_SPLITS * 66];
  float M = NEGF;
  for (int i = 0; i < TOK0_SPLITS; i++) M = fmaxf(M, p0[i * 66]);
  float L = 0.f, a = 0.f;
  for (int i = 0; i < TOK0_SPLITS; i++) {
    float sc = __expf(p0[i * 66] - M);
    L += sc * p0[i * 66 + 1];
    a += sc * p0[i * 66 + 2 + d];
  }
  oattn[((long)b * S_LEN) * 768 + h * 64 + d] = f2b(a / L);
}

extern "C" void kernel_launch(void* const* d_in, const int* in_sizes, int n_in,
                              void* d_out, int out_size, void* d_ws, size_t ws_size,
                              hipStream_t stream) {
  (void)in_sizes; (void)n_in; (void)out_size; (void)ws_size;
  const float* x   = (const float*)d_in[0];
  const float* Wq  = (const float*)d_in[1];
  const float* Wk  = (const float*)d_in[2];
  const float* Wv  = (const float*)d_in[3];
  const float* Wqg = (const float*)d_in[4];
  const float* Wkg = (const float*)d_in[5];
  const float* Wvg = (const float*)d_in[6];
  const float* Wo  = (const float*)d_in[7];
  const int* amask = (const int*)d_in[8];
  char* ws = (char*)d_ws;
  short* xb    = (short*)(ws);                 // 8192x768 bf16 (dead after gemm0)
  short* Vt    = (short*)(ws);                 // overlays xb: 24bh x 64d x 4096s bf16
  short* W5t   = (short*)(ws + 12582912);      // 3840x768 bf16 (B^T)
  short* Wot   = (short*)(ws + 18481152);      // 768x768  bf16 (B^T)
  short* qkv   = (short*)(ws + 19660800);      // 5 x (B,H,S,HD) bf16
  short* oattn = (short*)(ws + 82575360);      // 8192x768 bf16
  float* qgbuf = (float*)(ws + 95158272);      // 2x768 f32
  float* partb = (float*)(ws + 95164416);      // 24x16x66 f32
  float* mvb   = (float*)(ws + 95265792);      // 2x4096 f32 mask bias
  float* outf  = (float*)d_out;

  k_pre<<<9656, 256, 0, stream>>>(x, Wq, Wk, Wv, Wkg, Wvg, Wo, Wqg, amask,
                                  xb, W5t, Wot, qgbuf, mvb);
  k_gemm3<<<960, 512, 0, stream>>>(xb, W5t, 768, 0, qkv, nullptr);
  const short* Qb = qkv;
  const short* Kb = qkv + 6291456;
  const short* Vb = qkv + 2 * 6291456;
  const short* Kg = qkv + 3 * 6291456;
  const short* Vg = qkv + 4 * 6291456;
  k_vt<<<dim3(64, 24), 256, 0, stream>>>(Vb, Vt);  // xb is dead from here on
  k_attn<<<1920, 256, 0, stream>>>(Qb, Kb, Vb, Vt, Kg, Vg, qgbuf, amask, mvb, oattn, partb);
  k_tok0_comb<<<24, 64, 0, stream>>>(partb, oattn);
  k_gemm<<<384, 256, 0, stream>>>(oattn, Wot, 768, 1, nullptr, outf);
}

// Round 18
// 186.502 us; speedup vs baseline: 1.3498x; 1.3498x over previous
//
#include <hip/hip_runtime.h>

#define S_LEN 4096
#define NH 12
#define HDIM 64
#define DMODEL 768
#define NEGF -1.0e9f
#define TOK0_SPLITS 16
#define RSTH 16777216.0f  // 2^24 overflow guard for no-rmax softmax fast path

typedef __attribute__((ext_vector_type(8))) short bf16x8;
typedef __attribute__((ext_vector_type(4))) float f32x4;

__device__ __forceinline__ short f2b(float f) {
  union { float f; unsigned u; } v; v.f = f;
  unsigned r = v.u + 0x7fffu + ((v.u >> 16) & 1u);
  return (short)(r >> 16);
}
__device__ __forceinline__ float b2f(short s) {
  union { unsigned u; float f; } v; v.u = ((unsigned)(unsigned short)s) << 16;
  return v.f;
}

// ---------- fused preprocessing: conv_x | weight-transpose | mask-bias | qg ----------
__global__ __launch_bounds__(256) void k_pre(const float* __restrict__ x,
                                             const float* __restrict__ Wq,
                                             const float* __restrict__ Wk,
                                             const float* __restrict__ Wv,
                                             const float* __restrict__ Wkg,
                                             const float* __restrict__ Wvg,
                                             const float* __restrict__ Wo,
                                             const float* __restrict__ Wqg,
                                             const int* __restrict__ amask,
                                             short* __restrict__ xb,
                                             short* __restrict__ W5t,
                                             short* __restrict__ Wot,
                                             float* __restrict__ qg,
                                             float* __restrict__ mvb) {
  __shared__ float smem[1056];
  int bid = blockIdx.x, tid = threadIdx.x;
  if (bid < 6144) {  // ---- x f32 -> bf16 (x4) ----
    int i = bid * 256 + tid;
    float4 v = ((const float4*)x)[i];
    ((short4*)xb)[i] = make_short4(f2b(v.x), f2b(v.y), f2b(v.z), f2b(v.w));
  } else if (bid < 9600) {  // ---- weight transpose+convert ----
    int zb = bid - 6144;
    int z = zb / 576, rem = zb - z * 576;
    int by = rem / 24, bx = rem - by * 24;
    const float* src; float scale = 1.f; short* dst;
    switch (z) {
      case 0: src = Wq;  scale = 0.125f * 1.44269504f; dst = W5t; break;
      case 1: src = Wk;  dst = W5t + 589824; break;
      case 2: src = Wv;  dst = W5t + 2 * 589824; break;
      case 3: src = Wkg; dst = W5t + 3 * 589824; break;
      case 4: src = Wvg; dst = W5t + 4 * 589824; break;
      default: src = Wo; dst = Wot; break;
    }
    int tx = tid & 31, ty = tid >> 5;
    int kb = by * 32, nb = bx * 32;
    for (int i = 0; i < 4; i++) smem[(ty + 8 * i) * 33 + tx] = src[(kb + ty + 8 * i) * 768 + nb + tx];
    __syncthreads();
    for (int i = 0; i < 4; i++)
      dst[(nb + ty + 8 * i) * 768 + kb + tx] = f2b(smem[tx * 33 + ty + 8 * i] * scale);
  } else if (bid < 9632) {  // ---- mask bias ----
    int zb = bid - 9600;
    int b = zb >> 4, s = (zb & 15) * 256 + tid;
    mvb[b * S_LEN + s] = (s != 0 && amask[b * S_LEN + s] > 0) ? 0.f : NEGF;
  } else {  // ---- qg = x[b,0,:] @ Wqg * 0.125 ----
    int zb = bid - 9632;
    int h = zb % 12, b = zb / 12;
    int out = tid & 63, slice = tid >> 6;
    float* xr = smem;          // 768
    float* ps = smem + 768;    // 4*64
    for (int i = tid; i < 768; i += 256) xr[i] = x[(long)b * S_LEN * 768 + i];
    __syncthreads();
    float a = 0.f;
    int n = h * 64 + out;
#pragma unroll 8
    for (int k = slice * 192; k < slice * 192 + 192; k++) a += xr[k] * Wqg[k * 768 + n];
    ps[slice * 64 + out] = a;
    __syncthreads();
    if (tid < 64)
      qg[b * 768 + h * 64 + tid] = (ps[tid] + ps[64 + tid] + ps[128 + tid] + ps[192 + tid]) * 0.125f;
  }
}

// ---------- 256x128-tile bf16 GEMM: 8 waves (4Mx2N), proven 2-phase schedule ----------
// Per-wave state IDENTICAL to the proven 128^2 k_gemm (acc[4][4], same fragment
// reads, same __syncthreads dbuf). B-tile shared by 2x the A-rows -> staging
// bytes/MFMA drop 25%. VGPR 52, spill-free (R16 verified: 83.5us, WRITE 69MB).
__global__ __launch_bounds__(512) void k_gemm3(const short* __restrict__ A,
                                               const short* __restrict__ Bt, int K, int mode,
                                               short* __restrict__ qkv, float* __restrict__ outf) {
  __shared__ short Al[2][256 * 32];
  __shared__ short Bl[2][128 * 32];
  int bid = blockIdx.x;
  int xcd = bid & 7, ii = bid >> 3;
  int bm = xcd * 4 + (ii & 3), bn = ii >> 2;
  int tid = threadIdx.x;
  int bm0 = bm * 256, bn0 = bn * 128;
  int w = tid >> 6, lane = tid & 63, g = lane >> 4, r16 = lane & 15;
  int wm = w >> 1, wn = w & 1;
  f32x4 zero4 = {0.f, 0.f, 0.f, 0.f};
  f32x4 acc[4][4];
  for (int m = 0; m < 4; m++) for (int n = 0; n < 4; n++) acc[m][n] = zero4;
  int srow = tid >> 2;          // 0..127
  int scol = (tid & 3) * 8;     // 16B chunks
#define G_STAGE3(BUF, KT)                                                             \
  do {                                                                                \
    const short* ga0 = &A[(long)(bm0 + srow) * K + (KT) + scol];                      \
    __builtin_amdgcn_global_load_lds(                                                 \
        (const __attribute__((address_space(1))) void*)ga0,                           \
        (__attribute__((address_space(3))) void*)&Al[BUF][srow * 32 + scol], 16, 0, 0);\
    const short* ga1 = &A[(long)(bm0 + 128 + srow) * K + (KT) + scol];                \
    __builtin_amdgcn_global_load_lds(                                                 \
        (const __attribute__((address_space(1))) void*)ga1,                           \
        (__attribute__((address_space(3))) void*)&Al[BUF][(128 + srow) * 32 + scol],  \
        16, 0, 0);                                                                    \
    const short* gb = &Bt[(long)(bn0 + srow) * K + (KT) + scol];                      \
    __builtin_amdgcn_global_load_lds(                                                 \
        (const __attribute__((address_space(1))) void*)gb,                            \
        (__attribute__((address_space(3))) void*)&Bl[BUF][srow * 32 + scol], 16, 0, 0);\
  } while (0)
  int nt = K >> 5;
  G_STAGE3(0, 0);
  __syncthreads();
  int cur = 0;
  for (int t = 0; t < nt; t++) {
    if (t + 1 < nt) G_STAGE3(cur ^ 1, (t + 1) * 32);
    bf16x8 af[4], bfv[4];
    for (int m = 0; m < 4; m++)
      af[m] = *(const bf16x8*)&Al[cur][(wm * 64 + m * 16 + r16) * 32 + g * 8];
    for (int n = 0; n < 4; n++)
      bfv[n] = *(const bf16x8*)&Bl[cur][(wn * 64 + n * 16 + r16) * 32 + g * 8];
    for (int m = 0; m < 4; m++)
      for (int n = 0; n < 4; n++)
        acc[m][n] = __builtin_amdgcn_mfma_f32_16x16x32_bf16(af[m], bfv[n], acc[m][n], 0, 0, 0);
    __syncthreads();
    cur ^= 1;
  }
#undef G_STAGE3
  for (int m = 0; m < 4; m++)
    for (int n = 0; n < 4; n++)
      for (int reg = 0; reg < 4; reg++) {
        int row = bm0 + wm * 64 + m * 16 + g * 4 + reg;
        int col = bn0 + wn * 64 + n * 16 + r16;
        float val = acc[m][n][reg];
        if (mode == 0) {
          int proj = col / 768;
          int rem = col - proj * 768;
          int hh = rem >> 6, d = rem & 63;
          int bb = row >> 12, s = row & 4095;
          qkv[(long)proj * 6291456 + ((((long)bb * NH + hh) * S_LEN + s) << 6) + d] = f2b(val);
        } else {
          outf[(long)row * 768 + col] = val;
        }
      }
}

// ---------- 128x128-tile bf16 GEMM (proven; kept for the small output proj) ----------
__global__ __launch_bounds__(256) void k_gemm(const short* __restrict__ A,
                                              const short* __restrict__ Bt, int K, int mode,
                                              short* __restrict__ qkv, float* __restrict__ outf) {
  __shared__ short Al[2][128 * 32];
  __shared__ short Bl[2][128 * 32];
  int bid = blockIdx.x;
  int xcd = bid & 7, ii = bid >> 3;
  int bm = xcd * 8 + (ii & 7), bn = ii >> 3;
  int tid = threadIdx.x;
  int bm0 = bm * 128, bn0 = bn * 128;
  int w = tid >> 6, lane = tid & 63, g = lane >> 4, r16 = lane & 15;
  int wr = (w >> 1) * 64, wc = (w & 1) * 64;
  f32x4 zero4 = {0.f, 0.f, 0.f, 0.f};
  f32x4 acc[4][4];
  for (int m = 0; m < 4; m++) for (int n = 0; n < 4; n++) acc[m][n] = zero4;
  int srow = w * 32 + (lane >> 2);
  int scol = (lane & 3) * 8;
#define G_STAGE(BUF, KT)                                                              \
  do {                                                                                \
    for (int i = 0; i < 2; i++) {                                                     \
      const short* ga = &A[(long)(bm0 + srow + i * 16) * K + (KT) + scol];            \
      const short* gb = &Bt[(long)(bn0 + srow + i * 16) * K + (KT) + scol];           \
      __builtin_amdgcn_global_load_lds(                                               \
          (const __attribute__((address_space(1))) void*)ga,                          \
          (__attribute__((address_space(3))) void*)&Al[BUF][(w * 32 + i * 16) * 32],  \
          16, 0, 0);                                                                  \
      __builtin_amdgcn_global_load_lds(                                               \
          (const __attribute__((address_space(1))) void*)gb,                          \
          (__attribute__((address_space(3))) void*)&Bl[BUF][(w * 32 + i * 16) * 32],  \
          16, 0, 0);                                                                  \
    }                                                                                 \
  } while (0)
  int nt = K >> 5;
  G_STAGE(0, 0);
  __syncthreads();
  int cur = 0;
  for (int t = 0; t < nt; t++) {
    if (t + 1 < nt) G_STAGE(cur ^ 1, (t + 1) * 32);
    bf16x8 af[4], bfv[4];
    for (int m = 0; m < 4; m++) af[m] = *(const bf16x8*)&Al[cur][(wr + m * 16 + r16) * 32 + g * 8];
    for (int n = 0; n < 4; n++) bfv[n] = *(const bf16x8*)&Bl[cur][(wc + n * 16 + r16) * 32 + g * 8];
    for (int m = 0; m < 4; m++)
      for (int n = 0; n < 4; n++)
        acc[m][n] = __builtin_amdgcn_mfma_f32_16x16x32_bf16(af[m], bfv[n], acc[m][n], 0, 0, 0);
    __syncthreads();
    cur ^= 1;
  }
#undef G_STAGE
  for (int m = 0; m < 4; m++)
    for (int n = 0; n < 4; n++)
      for (int reg = 0; reg < 4; reg++) {
        int row = bm0 + wr + m * 16 + g * 4 + reg;
        int col = bn0 + wc + n * 16 + r16;
        float val = acc[m][n][reg];
        if (mode == 0) {
          int proj = col / 768;
          int rem = col - proj * 768;
          int hh = rem >> 6, d = rem & 63;
          int bb = row >> 12, s = row & 4095;
          qkv[(long)proj * 6291456 + ((((long)bb * NH + hh) * S_LEN + s) << 6) + d] = f2b(val);
        } else {
          outf[(long)row * 768 + col] = val;
        }
      }
}

// ---------- V transpose: Vt[b,h,d,s] from V[b,h,s,d] ----------
__global__ __launch_bounds__(256) void k_vt(const short* __restrict__ V, short* __restrict__ Vt) {
  __shared__ short buf[64][72];
  int st = blockIdx.x, bh = blockIdx.y;
  int tid = threadIdx.x;
  long base = (long)bh * S_LEN * HDIM;
  int s0 = st * 64;
  int r = tid >> 2, c = (tid & 3) * 16;
  *(int4*)&buf[r][c]     = *(const int4*)&V[base + (long)(s0 + r) * HDIM + c];
  *(int4*)&buf[r][c + 8] = *(const int4*)&V[base + (long)(s0 + r) * HDIM + c + 8];
  __syncthreads();
  int d = tid >> 2, sc = (tid & 3) * 16;
  short tmp[16];
#pragma unroll
  for (int j = 0; j < 16; j++) tmp[j] = buf[sc + j][d];
  long ob = base + (long)d * S_LEN + s0 + sc;
  *(int4*)&Vt[ob]     = *(const int4*)&tmp[0];
  *(int4*)&Vt[ob + 8] = *(const int4*)&tmp[8];
}

#define PSTRIDE 68 // Plds row stride (shorts)

// ---------- band attention per-chunk compute: no-rmax fast path + guarded fallback ----------
__device__ __forceinline__ void band_chunk(
    int ks0, int qrow0, int g, int r16,
    const bf16x8 (&qf)[2][2], const bf16x8 (&kf)[4][2], const bf16x8 (&vf)[4][2],
    const float (&mv)[4],
    float (&mstate)[2][4], float (&lstate)[2][4], f32x4 (&acc)[2][4],
    short* Plds) {
  int dlo = ks0 - qrow0;
  bool fullok = (dlo >= -224) && (dlo <= 192);  // wave-uniform
  for (int m = 0; m < 2; m++) {
    f32x4 s[4];
    f32x4 zero4 = {0.f, 0.f, 0.f, 0.f};
    for (int n = 0; n < 4; n++) {
      f32x4 z = __builtin_amdgcn_mfma_f32_16x16x32_bf16(qf[m][0], kf[n][0], zero4, 0, 0, 0);
      s[n] = __builtin_amdgcn_mfma_f32_16x16x32_bf16(qf[m][1], kf[n][1], z, 0, 0, 0);
    }
    float p[4][4];
    float rs[4] = {0.f, 0.f, 0.f, 0.f};
    int qbase = qrow0 + m * 16 + g * 4;
    if (fullok) {
      for (int n = 0; n < 4; n++)
        for (int reg = 0; reg < 4; reg++) {
          float e = __builtin_amdgcn_exp2f(s[n][reg] + mv[n] - mstate[m][reg]);
          p[n][reg] = e;
          rs[reg] += e;
        }
    } else {
      for (int n = 0; n < 4; n++) {
        int kpos = ks0 + n * 16 + r16;
        for (int reg = 0; reg < 4; reg++) {
          int qpos = qbase + reg;
          bool ok = (kpos >= qpos - 256) && (kpos <= qpos + 256);
          float e = ok ? __builtin_amdgcn_exp2f(s[n][reg] + mv[n] - mstate[m][reg]) : 0.f;
          p[n][reg] = e;
          rs[reg] += e;
        }
      }
    }
    bool ovf = (rs[0] > RSTH) || (rs[1] > RSTH) || (rs[2] > RSTH) || (rs[3] > RSTH);
    if (__any((int)ovf)) {
      // slow fallback: full online-softmax update recomputed from s (rare)
      float rmax[4];
      for (int reg = 0; reg < 4; reg++) rmax[reg] = NEGF;
      for (int n = 0; n < 4; n++) {
        int kpos = ks0 + n * 16 + r16;
        for (int reg = 0; reg < 4; reg++) {
          int qpos = qbase + reg;
          bool ok = fullok || ((kpos >= qpos - 256) && (kpos <= qpos + 256));
          float val = ok ? (s[n][reg] + mv[n]) : NEGF;
          rmax[reg] = fmaxf(rmax[reg], val);
        }
      }
      for (int reg = 0; reg < 4; reg++) {
        float r = rmax[reg];
        r = fmaxf(r, __shfl_xor(r, 1));
        r = fmaxf(r, __shfl_xor(r, 2));
        r = fmaxf(r, __shfl_xor(r, 4));
        r = fmaxf(r, __shfl_xor(r, 8));
        rmax[reg] = r;
      }
      float scal[4];
      for (int reg = 0; reg < 4; reg++) {
        float mn = fmaxf(mstate[m][reg], rmax[reg]);
        scal[reg] = __builtin_amdgcn_exp2f(mstate[m][reg] - mn);
        mstate[m][reg] = mn;
        rs[reg] = 0.f;
      }
      for (int n = 0; n < 4; n++) {
        int kpos = ks0 + n * 16 + r16;
        for (int reg = 0; reg < 4; reg++) {
          int qpos = qbase + reg;
          bool ok = fullok || ((kpos >= qpos - 256) && (kpos <= qpos + 256));
          float e = ok ? __builtin_amdgcn_exp2f(s[n][reg] + mv[n] - mstate[m][reg]) : 0.f;
          p[n][reg] = e;
          rs[reg] += e;
        }
      }
      for (int reg = 0; reg < 4; reg++) {
        float r = rs[reg];
        r += __shfl_xor(r, 1);
        r += __shfl_xor(r, 2);
        r += __shfl_xor(r, 4);
        r += __shfl_xor(r, 8);
        lstate[m][reg] = lstate[m][reg] * scal[reg] + r;
      }
      for (int n = 0; n < 4; n++)
        for (int reg = 0; reg < 4; reg++) acc[m][n][reg] *= scal[reg];
    } else {  // common path: no rmax, no rescale
      for (int reg = 0; reg < 4; reg++) {
        float r = rs[reg];
        r += __shfl_xor(r, 1);
        r += __shfl_xor(r, 2);
        r += __shfl_xor(r, 4);
        r += __shfl_xor(r, 8);
        lstate[m][reg] += r;
      }
    }
    for (int n = 0; n < 4; n++)
      for (int reg = 0; reg < 4; reg++)
        Plds[(g * 4 + reg) * PSTRIDE + n * 16 + r16] = f2b(p[n][reg]);
    bf16x8 pa[2];
    for (int ks = 0; ks < 2; ks++)
      pa[ks] = *(const bf16x8*)&Plds[r16 * PSTRIDE + ks * 32 + g * 8];
    for (int n = 0; n < 4; n++)
      for (int ks = 0; ks < 2; ks++)
        acc[m][n] = __builtin_amdgcn_mfma_f32_16x16x32_bf16(pa[ks], vf[n][ks], acc[m][n], 0, 0, 0);
  }
}

// ---------- fused attention: band 2-way split-KV (bid<1536) + tok0 (bid>=1536) ----------
// R16 configuration (best: 186.6us total). No register pipelining: the allocator
// caps this kernel at 128 VGPR regardless of launch_bounds and spills anything
// bigger (R17: 2-deep pipeline -> 166MB scratch, 144us). min-waves MUST stay 2
// (bound 4 -> 64-VGPR cap -> R9 spill).
__global__ __launch_bounds__(256, 2) void k_attn(const short* __restrict__ Qb,
                                                 const short* __restrict__ Kb,
                                                 const short* __restrict__ Vb,
                                                 const short* __restrict__ Vtb,
                                                 const short* __restrict__ Kg,
                                                 const short* __restrict__ Vg,
                                                 const float* __restrict__ qg,
                                                 const int* __restrict__ amask,
                                                 const float* __restrict__ mvb,
                                                 short* __restrict__ oattn,
                                                 float* __restrict__ part) {
  __shared__ short Plds[4][16 * PSTRIDE];
  __shared__ float mrg[2][48][65];
  __shared__ float fsm[592];
  int bid = blockIdx.x, tid = threadIdx.x;
  if (bid < 1536) {
    // ================= band path (2-way split-KV) =================
    int qt = bid & 63, rest = bid >> 6;
    int h = rest % NH, b = rest / NH;
    int w = tid >> 6, lane = tid & 63, g = lane >> 4, r16 = lane & 15;
    int pair = w >> 1;   // q-subtile (0: rows +0, 1: rows +32)
    int par = w & 1;     // KV-split parity
    long bhof = ((long)(b * NH + h)) * S_LEN * HDIM;
    int qrow0 = qt * 64 + pair * 32;

    bf16x8 qf[2][2];
    for (int m = 0; m < 2; m++)
      for (int ks = 0; ks < 2; ks++)
        qf[m][ks] = *(const bf16x8*)&Qb[bhof + (long)(qrow0 + m * 16 + r16) * HDIM + ks * 32 + g * 8];

    float mstate[2][4], lstate[2][4];
    f32x4 acc[2][4];
    if (par == 0) {  // parity 0 owns the global key-0 column init (clamped for fast path)
      bf16x8 k0f[2];
      for (int ks = 0; ks < 2; ks++) k0f[ks] = *(const bf16x8*)&Kb[bhof + ks * 32 + g * 8];
      float part0[2];
      for (int m = 0; m < 2; m++) {
        float p = 0.f;
        for (int ks = 0; ks < 2; ks++)
          for (int j = 0; j < 8; j++) p += b2f(qf[m][ks][j]) * b2f(k0f[ks][j]);
        p += __shfl_xor(p, 16);
        p += __shfl_xor(p, 32);
        part0[m] = p;
      }
      float mask0 = (amask[b * S_LEN] > 0) ? 0.f : NEGF;
      float v0v[4];
      for (int n = 0; n < 4; n++) v0v[n] = b2f(Vb[bhof + n * 16 + r16]);
      for (int m = 0; m < 2; m++)
        for (int reg = 0; reg < 4; reg++) {
          float m0raw = __shfl(part0[m], g * 4 + reg) + mask0;
          float m0 = fmaxf(m0raw, -60.f);  // clamp so fast-path exp2 stays finite
          mstate[m][reg] = m0;
          float l0 = __builtin_amdgcn_exp2f(m0raw - m0);
          lstate[m][reg] = l0;
          for (int n = 0; n < 4; n++) acc[m][n][reg] = l0 * v0v[n];
        }
    } else {  // parity 1: m=0 (finite: fast path needs it), l=0, acc=0
      for (int m = 0; m < 2; m++)
        for (int reg = 0; reg < 4; reg++) {
          mstate[m][reg] = 0.f;
          lstate[m][reg] = 0.f;
          for (int n = 0; n < 4; n++) acc[m][n][reg] = 0.f;
        }
    }

    int wlo = (qrow0 - 256) >> 6; if (wlo < 0) wlo = 0;
    int whi = (qrow0 + 31 + 256) >> 6; if (whi > 63) whi = 63;

    for (int ci = wlo + par; ci <= whi; ci += 2) {
      int ks0 = ci * 64;
      // all global loads issued up front: latency hides under QK^T + softmax
      bf16x8 vf[4][2], kf[4][2];
      for (int n = 0; n < 4; n++)
        for (int ks = 0; ks < 2; ks++) {
          vf[n][ks] = *(const bf16x8*)&Vtb[bhof + (long)(n * 16 + r16) * S_LEN + ks0 + ks * 32 + g * 8];
          kf[n][ks] = *(const bf16x8*)&Kb[bhof + (long)(ks0 + n * 16 + r16) * HDIM + ks * 32 + g * 8];
        }
      float mv[4];
      for (int n = 0; n < 4; n++) mv[n] = mvb[b * S_LEN + ks0 + n * 16 + r16];
      band_chunk(ks0, qrow0, g, r16, qf, kf, vf, mv, mstate, lstate, acc, &Plds[w][0]);
    }

    // merge parity-1 state into parity-0, then write
    if (par == 1) {
      for (int m = 0; m < 2; m++)
        for (int reg = 0; reg < 4; reg++) {
          mrg[pair][m * 4 + reg][lane] = mstate[m][reg];
          mrg[pair][8 + m * 4 + reg][lane] = lstate[m][reg];
          for (int n = 0; n < 4; n++)
            mrg[pair][16 + m * 16 + n * 4 + reg][lane] = acc[m][n][reg];
        }
    }
    __syncthreads();
    if (par == 0) {
      for (int m = 0; m < 2; m++)
        for (int reg = 0; reg < 4; reg++) {
          float mB = mrg[pair][m * 4 + reg][lane];
          float lB = mrg[pair][8 + m * 4 + reg][lane];
          float M = fmaxf(mstate[m][reg], mB);
          float sA = __builtin_amdgcn_exp2f(mstate[m][reg] - M);
          float sB = __builtin_amdgcn_exp2f(mB - M);
          float l = lstate[m][reg] * sA + lB * sB;
          int token = qrow0 + m * 16 + g * 4 + reg;
          for (int n = 0; n < 4; n++) {
            float a = acc[m][n][reg] * sA + mrg[pair][16 + m * 16 + n * 4 + reg][lane] * sB;
            int col = h * 64 + n * 16 + r16;
            oattn[((long)b * S_LEN + token) * 768 + col] = f2b(a / l);
          }
        }
    }
  } else {
    // ================= token-0 global attention partials =================
    int tbid = bid - 1536;
    int split = tbid & 15, bhid = tbid >> 4;
    int b = bhid / NH, h = bhid % NH;
    long base = (long)bhid * S_LEN * HDIM;
    int lane = tid & 63, w = tid >> 6;
    int s = split * 256 + tid;
    float* qgl  = fsm;        // 64
    float* p_sh = fsm + 64;   // 256
    float* red  = fsm + 320;  // 4
    float* psum = fsm + 324;  // 4*64
    if (tid < 64) qgl[tid] = qg[b * 768 + h * 64 + tid];
    __syncthreads();
    float dot = 0.f;
    {
      const int4* kr = (const int4*)&Kg[base + (long)s * HDIM];
#pragma unroll
      for (int u = 0; u < 8; u++) {
        int4 pk = kr[u];
        const short* sp = (const short*)&pk;
        for (int j = 0; j < 8; j++) dot += qgl[u * 8 + j] * b2f(sp[j]);
      }
      dot += (amask[b * S_LEN + s] > 0) ? 0.f : NEGF;
    }
    float mx = dot;
    for (int o = 32; o; o >>= 1) mx = fmaxf(mx, __shfl_xor(mx, o));
    if (lane == 0) red[w] = mx;
    __syncthreads();
    mx = fmaxf(fmaxf(red[0], red[1]), fmaxf(red[2], red[3]));
    float e = __expf(dot - mx);
    p_sh[tid] = e;
    float sum = e;
    for (int o = 32; o; o >>= 1) sum += __shfl_xor(sum, o);
    __syncthreads();
    if (lane == 0) red[w] = sum;
    __syncthreads();
    sum = red[0] + red[1] + red[2] + red[3];
    int d = tid & 63, grp = tid >> 6;
    float a = 0.f;
    long vb = base + (long)(split * 256 + grp * 64) * HDIM + d;
#pragma unroll 8
    for (int j = 0; j < 64; j++) a += p_sh[grp * 64 + j] * b2f(Vg[vb + (long)j * HDIM]);
    psum[grp * 64 + d] = a;
    __syncthreads();
    float* dst = &part[((long)bhid * TOK0_SPLITS + split) * 66];
    if (tid == 0) { dst[0] = mx; dst[1] = sum; }
    if (tid < 64)
      dst[2 + tid] = psum[tid] + psum[64 + tid] + psum[128 + tid] + psum[192 + tid];
  }
}

__global__ void k_tok0_comb(const float* __restrict__ part, short* __restrict__ oattn) {
  int bhid = blockIdx.x, d = threadIdx.x;
  int b = bhid / NH, h = bhid % NH;
  const float* p0 = &part[(long)bhid * TOK0_SPLITS * 66];
  float M = NEGF;
  for (int i = 0; i < TOK0_SPLITS; i++) M = fmaxf(M, p0[i * 66]);
  float L = 0.f, a = 0.f;
  for (int i = 0; i < TOK0_SPLITS; i++) {
    float sc = __expf(p0[i * 66] - M);
    L += sc * p0[i * 66 + 1];
    a += sc * p0[i * 66 + 2 + d];
  }
  oattn[((long)b * S_LEN) * 768 + h * 64 + d] = f2b(a / L);
}

extern "C" void kernel_launch(void* const* d_in, const int* in_sizes, int n_in,
                              void* d_out, int out_size, void* d_ws, size_t ws_size,
                              hipStream_t stream) {
  (void)in_sizes; (void)n_in; (void)out_size; (void)ws_size;
  const float* x   = (const float*)d_in[0];
  const float* Wq  = (const float*)d_in[1];
  const float* Wk  = (const float*)d_in[2];
  const float* Wv  = (const float*)d_in[3];
  const float* Wqg = (const float*)d_in[4];
  const float* Wkg = (const float*)d_in[5];
  const float* Wvg = (const float*)d_in[6];
  const float* Wo  = (const float*)d_in[7];
  const int* amask = (const int*)d_in[8];
  char* ws = (char*)d_ws;
  short* xb    = (short*)(ws);                 // 8192x768 bf16 (dead after gemm0)
  short* Vt    = (short*)(ws);                 // overlays xb: 24bh x 64d x 4096s bf16
  short* W5t   = (short*)(ws + 12582912);      // 3840x768 bf16 (B^T)
  short* Wot   = (short*)(ws + 18481152);      // 768x768  bf16 (B^T)
  short* qkv   = (short*)(ws + 19660800);      // 5 x (B,H,S,HD) bf16
  short* oattn = (short*)(ws + 82575360);      // 8192x768 bf16
  float* qgbuf = (float*)(ws + 95158272);      // 2x768 f32
  float* partb = (float*)(ws + 95164416);      // 24x16x66 f32
  float* mvb   = (float*)(ws + 95265792);      // 2x4096 f32 mask bias
  float* outf  = (float*)d_out;

  k_pre<<<9656, 256, 0, stream>>>(x, Wq, Wk, Wv, Wkg, Wvg, Wo, Wqg, amask,
                                  xb, W5t, Wot, qgbuf, mvb);
  k_gemm3<<<960, 512, 0, stream>>>(xb, W5t, 768, 0, qkv, nullptr);
  const short* Qb = qkv;
  const short* Kb = qkv + 6291456;
  const short* Vb = qkv + 2 * 6291456;
  const short* Kg = qkv + 3 * 6291456;
  const short* Vg = qkv + 4 * 6291456;
  k_vt<<<dim3(64, 24), 256, 0, stream>>>(Vb, Vt);  // xb is dead from here on
  k_attn<<<1920, 256, 0, stream>>>(Qb, Kb, Vb, Vt, Kg, Vg, qgbuf, amask, mvb, oattn, partb);
  k_tok0_comb<<<24, 64, 0, stream>>>(partb, oattn);
  k_gemm<<<384, 256, 0, stream>>>(oattn, Wot, 768, 1, nullptr, outf);
}